// Round 6
// baseline (77.095 us; speedup 1.0000x reference)
//
#include <hip/hip_runtime.h>
#include <cstddef>
#include <cstdint>

#define BETA 0.05f

typedef unsigned short u16;
typedef unsigned int u32;
typedef __attribute__((ext_vector_type(8))) short bf16x8;
typedef __attribute__((ext_vector_type(4))) float f32x4;
typedef __attribute__((ext_vector_type(4))) u32 u32x4;

constexpr int NQ = 8192;
constexpr int NK = 8192;
constexpr int DH = 128;
constexpr int DA = 160;              // padded aug depth: 128 data + b2_hi + b2_lo + 30 zeros
constexpr int SPLITS = 8;
constexpr int CHUNK = NK / SPLITS;   // 1024
constexpr int KVB = 32;
constexpr int STEPS = CHUNK / KVB;   // 32
constexpr int KSTRIDE = 336;         // 21*16B (odd slot count -> bank spread)
constexpr int KTILE = 32 * KSTRIDE;  // 10752
constexpr int VSTRIDE = 80;          // 5*16B
constexpr int VTILE = 128 * VSTRIDE; // 10240

__device__ __forceinline__ u16 f2bf(float x) {
  union { float f; u32 u; } v; v.f = x;
  u32 r = (v.u + 0x7fffu + ((v.u >> 16) & 1u)) >> 16;
  return (u16)r;
}

// ---------- prep: fused Q/K augmented bf16 casts + row stats ----------
__global__ void prep_qk(const float* __restrict__ Q, const float* __restrict__ ldq,
                        const float* __restrict__ K, const float* __restrict__ ldk,
                        const float* __restrict__ h, u16* __restrict__ Qa,
                        u16* __restrict__ Ka, float* __restrict__ arow) {
  const int bi = blockIdx.x;
  const int lane = threadIdx.x & 63;
  if (bi < NQ / 4) {
    const int row = bi * 4 + (threadIdx.x >> 6);
    const float2 q2 = *(const float2*)(Q + (size_t)row * DH + lane * 2);
    float sq = q2.x * q2.x + q2.y * q2.y;
#pragma unroll
    for (int off = 32; off > 0; off >>= 1) sq += __shfl_xor(sq, off);
    const float SC = 2.0f * BETA * 1.4426950408889634f;  // fold 2*beta*log2e
    ushort2 o; o.x = f2bf(SC * q2.x); o.y = f2bf(SC * q2.y);
    *(ushort2*)(Qa + (size_t)row * DA + lane * 2) = o;
    if (lane < 16) {
      ushort2 a;
      if (lane == 0) { a.x = 0x3F80; a.y = 0x3F80; } else { a.x = 0; a.y = 0; }
      *(ushort2*)(Qa + (size_t)row * DA + 128 + lane * 2) = a;
    }
    if (lane == 0) arow[row] = -BETA * sq - ldq[row] + logf(h[row]);
  } else {
    const int row = (bi - NQ / 4) * 4 + (threadIdx.x >> 6);
    const float2 k2 = *(const float2*)(K + (size_t)row * DH + lane * 2);
    float sq = k2.x * k2.x + k2.y * k2.y;
#pragma unroll
    for (int off = 32; off > 0; off >>= 1) sq += __shfl_xor(sq, off);
    ushort2 o; o.x = f2bf(k2.x); o.y = f2bf(k2.y);
    *(ushort2*)(Ka + (size_t)row * DA + lane * 2) = o;
    if (lane < 16) {
      ushort2 a; a.x = 0; a.y = 0;
      if (lane == 0) {
        const float b2 = (-BETA * sq - ldk[row] - logf(h[row])) * 1.4426950408889634f;
        const u16 bh = f2bf(b2);
        union { u32 u; float f; } hf; hf.u = ((u32)bh) << 16;
        const u16 bl = f2bf(b2 - hf.f);
        a.x = bh; a.y = bl;
      }
      *(ushort2*)(Ka + (size_t)row * DA + 128 + lane * 2) = a;
    }
  }
}

// V (M x D) -> VT (D x M) bf16
__global__ void prep_vt(const float* __restrict__ V, u16* __restrict__ VTb) {
  __shared__ float tile[64][65];
  const int j0 = blockIdx.x * 64;
  const int d0 = blockIdx.y * 64;
  const int t = threadIdx.x;
  const int r = t >> 4;
  const int c = (t & 15) * 4;
#pragma unroll
  for (int rr = r; rr < 64; rr += 16) {
    const float4 v = *(const float4*)(V + (size_t)(j0 + rr) * DH + d0 + c);
    tile[rr][c + 0] = v.x; tile[rr][c + 1] = v.y;
    tile[rr][c + 2] = v.z; tile[rr][c + 3] = v.w;
  }
  __syncthreads();
#pragma unroll
  for (int dd = r; dd < 64; dd += 16) {
    ushort4 o;
    o.x = f2bf(tile[c + 0][dd]);
    o.y = f2bf(tile[c + 1][dd]);
    o.z = f2bf(tile[c + 2][dd]);
    o.w = f2bf(tile[c + 3][dd]);
    *(ushort4*)(VTb + (size_t)(d0 + dd) * NK + j0 + c) = o;
  }
}

// ---------- main: 8 waves x 16 q-rows (16x16x32), 8-way KV split ----------
__global__ __launch_bounds__(512, 4) void attn_main(
    const u16* __restrict__ Qa, const u16* __restrict__ Ka,
    const u16* __restrict__ VTb, u16* __restrict__ Opart,
    float* __restrict__ Lpart) {
  __shared__ __align__(16) char lds[2 * KTILE + 2 * VTILE];  // 41984 B
  char* ldsK = lds;
  char* ldsV = lds + 2 * KTILE;

  const int tid = threadIdx.x;
  const int wid = tid >> 6;
  const int lane = tid & 63;
  const int g = lane >> 4;      // 0..3
  const int ln15 = lane & 15;
  const int bi = blockIdx.x;
  const int ks = bi & 7;        // split id -> XCD (L2 chunk locality)
  const int qg = bi >> 3;
  const int kvbase = ks * CHUNK;
  const int qrow0 = qg * 128 + wid * 16;

  // K staging map (640 16B-chunks per 32-row tile; 512 + 128 threads)
  const int kr0 = tid / 20, kc0 = tid % 20;
  const int kr1 = (512 + tid) / 20, kc1 = (512 + tid) % 20;

  // Q fragments (B-operand): col q = ln15, k = sl*32 + g*8 + j
  bf16x8 qf[5];
#pragma unroll
  for (int sl = 0; sl < 5; ++sl)
    qf[sl] = *(const bf16x8*)((const char*)Qa + (size_t)(qrow0 + ln15) * 320 + sl * 64 + g * 16);

  f32x4 acc[8];
#pragma unroll
  for (int dt = 0; dt < 8; ++dt) acc[dt] = (f32x4){0.f, 0.f, 0.f, 0.f};
  float lsum = 0.0f;

  u32x4 kregA, kregB, vreg;
  const char* KaB = (const char*)Ka + (size_t)kvbase * 320;
  const char* VTB = (const char*)VTb + (size_t)(tid >> 2) * (NK * 2) + (size_t)kvbase * 2 + (tid & 3) * 16;

  char* kd0 = ldsK + kr0 * KSTRIDE + kc0 * 16;
  char* kd1 = ldsK + kr1 * KSTRIDE + kc1 * 16;
  char* vd0 = ldsV + (tid >> 2) * VSTRIDE + (tid & 3) * 16;
  const char* kb0 = ldsK + ln15 * KSTRIDE + g * 16;
  const char* kb1 = ldsK + (16 + ln15) * KSTRIDE + g * 16;
  const char* vb0 = ldsV + ln15 * VSTRIDE + g * 16;

  auto issueLoads = [&](int step) {
    const char* ksrc = KaB + (size_t)step * (KVB * 320);
    kregA = *(const u32x4*)(ksrc + kr0 * 320 + kc0 * 16);
    if (tid < 128) kregB = *(const u32x4*)(ksrc + kr1 * 320 + kc1 * 16);
    vreg = *(const u32x4*)(VTB + (size_t)step * (KVB * 2));
  };
  auto writeLds = [&](int buf) {
    *(u32x4*)(kd0 + buf * KTILE) = kregA;
    if (tid < 128) *(u32x4*)(kd1 + buf * KTILE) = kregB;
    *(u32x4*)(vd0 + buf * VTILE) = vreg;
  };

  issueLoads(0);
  writeLds(0);
  __syncthreads();

  for (int t = 0; t < STEPS; ++t) {
    const int cur = t & 1;
    if (t < STEPS - 1) issueLoads(t + 1);  // T14: issue early, write after compute

    const char* kbA = kb0 + cur * KTILE;
    const char* kbB = kb1 + cur * KTILE;
    const char* vb = vb0 + cur * VTILE;

    // ---- swapped QK^T: two 16x16 S^T tiles (kv rows x q cols) ----
    f32x4 s0 = (f32x4){0.f, 0.f, 0.f, 0.f};
    f32x4 s1 = (f32x4){0.f, 0.f, 0.f, 0.f};
#pragma unroll
    for (int sl = 0; sl < 5; ++sl) {
      const bf16x8 kf0 = *(const bf16x8*)(kbA + sl * 64);
      const bf16x8 kf1 = *(const bf16x8*)(kbB + sl * 64);
      s0 = __builtin_amdgcn_mfma_f32_16x16x32_bf16(kf0, qf[sl], s0, 0, 0, 0);
      s1 = __builtin_amdgcn_mfma_f32_16x16x32_bf16(kf1, qf[sl], s1, 0, 0, 0);
    }

    // ---- P = exp2(s2); s2 bounded ~[-25, 6] -> no max tracking ----
    float p[8];
#pragma unroll
    for (int r = 0; r < 4; ++r) { p[r] = exp2f(s0[r]); p[4 + r] = exp2f(s1[r]); }
    lsum += ((p[0] + p[1]) + (p[2] + p[3])) + ((p[4] + p[5]) + (p[6] + p[7]));

    // ---- pack to bf16: pk0/pk1 = kv quad g (tile0), pk2/pk3 = quad 4+g ----
    u32 pk0, pk1, pk2, pk3;
    asm("v_cvt_pk_bf16_f32 %0, %1, %2" : "=v"(pk0) : "v"(p[0]), "v"(p[1]));
    asm("v_cvt_pk_bf16_f32 %0, %1, %2" : "=v"(pk1) : "v"(p[2]), "v"(p[3]));
    asm("v_cvt_pk_bf16_f32 %0, %1, %2" : "=v"(pk2) : "v"(p[4]), "v"(p[5]));
    asm("v_cvt_pk_bf16_f32 %0, %1, %2" : "=v"(pk3) : "v"(p[6]), "v"(p[7]));

    // ---- redistribute quads: lane group g needs kv quads {2g, 2g+1} ----
    const bool odd = (g & 1);
    const u32 A = odd ? pk0 : pk2, B = odd ? pk1 : pk3;
    const u32 C = odd ? pk2 : pk0, D = odd ? pk3 : pk1;
    const u32 x16a = (u32)__shfl_xor((int)A, 16);
    const u32 x16b = (u32)__shfl_xor((int)B, 16);
    const u32 x32a = (u32)__shfl_xor((int)A, 32);
    const u32 x32b = (u32)__shfl_xor((int)B, 32);
    const u32 x48a = (u32)__shfl_xor((int)C, 48);
    const u32 x48b = (u32)__shfl_xor((int)D, 48);
    union { u32x4 u; bf16x8 b; } pa;
    pa.u[0] = (g == 0) ? pk0 : (g == 1) ? x48a : (g == 2) ? x32a : x16a;
    pa.u[1] = (g == 0) ? pk1 : (g == 1) ? x48b : (g == 2) ? x32b : x16b;
    pa.u[2] = (g == 0) ? x16a : (g == 1) ? x32a : (g == 2) ? x48a : pk2;
    pa.u[3] = (g == 0) ? x16b : (g == 1) ? x32b : (g == 2) ? x48b : pk3;

    // ---- PV: O[16q][128d], 8 d-tiles, one k-slice (kv=32) each ----
#pragma unroll
    for (int dt = 0; dt < 8; ++dt) {
      const bf16x8 vf = *(const bf16x8*)(vb + dt * (16 * VSTRIDE));
      acc[dt] = __builtin_amdgcn_mfma_f32_16x16x32_bf16(pa.b, vf, acc[dt], 0, 0, 0);
    }

    if (t < STEPS - 1) {
      writeLds(cur ^ 1);
      __syncthreads();
    }
  }

  // ---- epilogue: reduce L across 4 lane groups, write bf16 partials ----
  lsum += __shfl_xor(lsum, 16);
  lsum += __shfl_xor(lsum, 32);
  u16* op = Opart + ((size_t)ks * NQ + qrow0) * DH;
#pragma unroll
  for (int dt = 0; dt < 8; ++dt)
#pragma unroll
    for (int r = 0; r < 4; ++r)
      op[(size_t)(g * 4 + r) * DH + dt * 16 + ln15] = f2bf(acc[dt][r]);
  if (lane < 16) Lpart[(size_t)ks * NQ + qrow0 + ln15] = lsum;
}

// ---------- combine: plain sums over splits ----------
__global__ void combine(const u16* __restrict__ Opart, const float* __restrict__ Lpart,
                        const float* __restrict__ arow, float* __restrict__ out,
                        float* __restrict__ lse) {
  const int idx = blockIdx.x * 256 + threadIdx.x;
  const int row = idx >> 5;
  const int d4 = (idx & 31) * 4;
  float o0 = 0.f, o1 = 0.f, o2 = 0.f, o3 = 0.f;
  float L = 0.f;
#pragma unroll
  for (int s = 0; s < SPLITS; ++s) {
    const ushort4 v = *(const ushort4*)(Opart + ((size_t)s * NQ + row) * DH + d4);
    union { u32 u; float f; } c0, c1, c2, c3;
    c0.u = ((u32)v.x) << 16; c1.u = ((u32)v.y) << 16;
    c2.u = ((u32)v.z) << 16; c3.u = ((u32)v.w) << 16;
    o0 += c0.f; o1 += c1.f; o2 += c2.f; o3 += c3.f;
    L += Lpart[(size_t)s * NQ + row];
  }
  const float inv = 1.0f / L;
  *(float4*)(out + (size_t)row * DH + d4) =
      make_float4(o0 * inv, o1 * inv, o2 * inv, o3 * inv);
  if ((idx & 31) == 0) lse[row] = logf(L) + arow[row];
}

extern "C" void kernel_launch(void* const* d_in, const int* in_sizes, int n_in,
                              void* d_out, int out_size, void* d_ws, size_t ws_size,
                              hipStream_t stream) {
  const float* Q = (const float*)d_in[0];
  const float* K = (const float*)d_in[1];
  const float* V = (const float*)d_in[2];
  const float* h = (const float*)d_in[3];
  const float* ldq = (const float*)d_in[4];
  const float* ldk = (const float*)d_in[5];

  char* ws = (char*)d_ws;
  u16* Qa    = (u16*)(ws + 0);                       // 8192*160*2 = 2621440
  u16* Ka    = (u16*)(ws + 2621440);                 // 2621440
  u16* VTb   = (u16*)(ws + 5242880);                 // 2097152
  float* arow  = (float*)(ws + 7340032);             // 32768
  u16* Opart = (u16*)(ws + 7372800);                 // 8*8192*128*2 = 16777216
  float* Lpart = (float*)(ws + 24150016);            // 8*8192*4 = 262144 (end 24412160)

  float* out = (float*)d_out;
  float* lse = out + (size_t)NQ * DH;

  prep_qk<<<NQ / 2, 256, 0, stream>>>(Q, ldq, K, ldk, h, Qa, Ka, arow);
  prep_vt<<<dim3(NK / 64, DH / 64), 256, 0, stream>>>(V, VTb);
  attn_main<<<(NQ / 128) * SPLITS, 512, 0, stream>>>(Qa, Ka, VTb, Opart, Lpart);
  combine<<<NQ * 32 / 256, 256, 0, stream>>>(Opart, Lpart, arow, out, lse);
}

// Round 8
// 63.151 us; speedup vs baseline: 1.2208x; 1.2208x over previous
//
#include <hip/hip_runtime.h>
#include <cstddef>
#include <cstdint>

#define BETA 0.05f

typedef unsigned short u16;
typedef unsigned int u32;
typedef __attribute__((ext_vector_type(8))) short bf16x8;
typedef __attribute__((ext_vector_type(16))) float f32x16;
typedef __attribute__((ext_vector_type(4))) u32 u32x4;

constexpr int NQ = 8192;
constexpr int NK = 8192;
constexpr int DH = 128;
constexpr int DA = 144;              // augmented depth: 128 data + b2_hi + b2_lo + 14 zeros
constexpr int SPLITS = 8;
constexpr int CHUNK = NK / SPLITS;   // 1024
constexpr int KVB = 64;              // kv rows per step (m214: KVBLK 32->64 = +27%)
constexpr int STEPS = CHUNK / KVB;   // 16
constexpr int KSTRIDE = 304;         // 19*16B (odd slot count -> bank spread; col 18 = pad, unread)
constexpr int KTILE = KVB * KSTRIDE;   // 19456
constexpr int VSTRIDE = 144;         // 9*16B (64 kv * 2B + 16 pad)
constexpr int VTILE = 128 * VSTRIDE;   // 18432
constexpr int LDS_BYTES = 2 * KTILE + 2 * VTILE;  // 75776

__device__ __forceinline__ u16 f2bf(float x) {
  union { float f; u32 u; } v; v.f = x;
  u32 r = (v.u + 0x7fffu + ((v.u >> 16) & 1u)) >> 16;
  return (u16)r;
}

// ---------- prep: fused Q/K augmented bf16 casts + row stats ----------
__global__ void prep_qk(const float* __restrict__ Q, const float* __restrict__ ldq,
                        const float* __restrict__ K, const float* __restrict__ ldk,
                        const float* __restrict__ h, u16* __restrict__ Qa,
                        u16* __restrict__ Ka, float* __restrict__ arow) {
  const int bi = blockIdx.x;
  const int lane = threadIdx.x & 63;
  if (bi < NQ / 4) {
    const int row = bi * 4 + (threadIdx.x >> 6);
    const float2 q2 = *(const float2*)(Q + (size_t)row * DH + lane * 2);
    float sq = q2.x * q2.x + q2.y * q2.y;
#pragma unroll
    for (int off = 32; off > 0; off >>= 1) sq += __shfl_xor(sq, off);
    const float SC = 2.0f * BETA * 1.4426950408889634f;  // fold 2*beta*log2e
    ushort2 o; o.x = f2bf(SC * q2.x); o.y = f2bf(SC * q2.y);
    *(ushort2*)(Qa + (size_t)row * DA + lane * 2) = o;
    if (lane < 8) {
      ushort2 a;
      if (lane == 0) { a.x = 0x3F80; a.y = 0x3F80; } else { a.x = 0; a.y = 0; }
      *(ushort2*)(Qa + (size_t)row * DA + 128 + lane * 2) = a;
    }
    if (lane == 0) arow[row] = -BETA * sq - ldq[row] + logf(h[row]);
  } else {
    const int row = (bi - NQ / 4) * 4 + (threadIdx.x >> 6);
    const float2 k2 = *(const float2*)(K + (size_t)row * DH + lane * 2);
    float sq = k2.x * k2.x + k2.y * k2.y;
#pragma unroll
    for (int off = 32; off > 0; off >>= 1) sq += __shfl_xor(sq, off);
    ushort2 o; o.x = f2bf(k2.x); o.y = f2bf(k2.y);
    *(ushort2*)(Ka + (size_t)row * DA + lane * 2) = o;
    if (lane < 8) {
      ushort2 a; a.x = 0; a.y = 0;
      if (lane == 0) {
        const float b2 = (-BETA * sq - ldk[row] - logf(h[row])) * 1.4426950408889634f;
        const u16 bh = f2bf(b2);
        union { u32 u; float f; } hf; hf.u = ((u32)bh) << 16;
        const u16 bl = f2bf(b2 - hf.f);
        a.x = bh; a.y = bl;
      }
      *(ushort2*)(Ka + (size_t)row * DA + 128 + lane * 2) = a;
    }
  }
}

// V (M x D) -> VT (D x M) bf16
__global__ void prep_vt(const float* __restrict__ V, u16* __restrict__ VTb) {
  __shared__ float tile[64][65];
  const int j0 = blockIdx.x * 64;
  const int d0 = blockIdx.y * 64;
  const int t = threadIdx.x;
  const int r = t >> 4;
  const int c = (t & 15) * 4;
#pragma unroll
  for (int rr = r; rr < 64; rr += 16) {
    const float4 v = *(const float4*)(V + (size_t)(j0 + rr) * DH + d0 + c);
    tile[rr][c + 0] = v.x; tile[rr][c + 1] = v.y;
    tile[rr][c + 2] = v.z; tile[rr][c + 3] = v.w;
  }
  __syncthreads();
#pragma unroll
  for (int dd = r; dd < 64; dd += 16) {
    ushort4 o;
    o.x = f2bf(tile[c + 0][dd]);
    o.y = f2bf(tile[c + 1][dd]);
    o.z = f2bf(tile[c + 2][dd]);
    o.w = f2bf(tile[c + 3][dd]);
    *(ushort4*)(VTb + (size_t)(d0 + dd) * NK + j0 + c) = o;
  }
}

// ---------- main: 8 waves x 32 q-rows, KVB=64, swapped QK^T, setprio ----------
__global__ __launch_bounds__(512) void attn_main(
    const u16* __restrict__ Qa, const u16* __restrict__ Ka,
    const u16* __restrict__ VTb, u16* __restrict__ Opart,
    float* __restrict__ Lpart) {
  extern __shared__ __align__(16) char lds[];   // 75776 B (dynamic)
  char* ldsK = lds;
  char* ldsV = lds + 2 * KTILE;

  const int tid = threadIdx.x;
  const int wid = tid >> 6;
  const int lane = tid & 63;
  const int hi = lane >> 5;
  const int ln31 = lane & 31;
  const int bi = blockIdx.x;
  const int ks = bi & 7;          // split id -> XCD (L2 chunk locality)
  const int qg = bi >> 3;
  const int kvbase = ks * CHUNK;
  const int qrow0 = qg * 256 + wid * 32;

  // K staging: 64 rows x 18 data-chunks(16B) = 1152 chunks over 512+512+128
  const int cA = tid, cB = 512 + tid, cC = 1024 + tid;
  const int kAsrc = (cA / 18) * 288 + (cA % 18) * 16;
  const int kBsrc = (cB / 18) * 288 + (cB % 18) * 16;
  const int kCsrc = (cC / 18) * 288 + (cC % 18) * 16;
  const int kAdst = (cA / 18) * KSTRIDE + (cA % 18) * 16;
  const int kBdst = (cB / 18) * KSTRIDE + (cB % 18) * 16;
  const int kCdst = (cC / 18) * KSTRIDE + (cC % 18) * 16;
  // V staging: 128 rows x 8 chunks = 1024 chunks over 512 threads (x2)
  const int vAdst = (tid >> 3) * VSTRIDE + (tid & 7) * 16;
  const int vBdst = ((512 + tid) >> 3) * VSTRIDE + (tid & 7) * 16;

  // Q fragments (B-operand): col q = ln31, k(d) = sl*16 + hi*8 + j
  bf16x8 qf[9];
#pragma unroll
  for (int sl = 0; sl < 9; ++sl)
    qf[sl] = *(const bf16x8*)((const char*)Qa + (size_t)(qrow0 + ln31) * 288 + sl * 32 + hi * 16);

  f32x16 acc[4];
#pragma unroll
  for (int dt = 0; dt < 4; ++dt)
#pragma unroll
    for (int r = 0; r < 16; ++r) acc[dt][r] = 0.0f;
  float lsum = 0.0f;

  u32x4 kregA, kregB, kregC, vreg0, vreg1;
  const char* KaB = (const char*)Ka + (size_t)kvbase * 288;
  const char* VT0 = (const char*)VTb + (size_t)(tid >> 3) * (NK * 2) + (size_t)kvbase * 2 + (tid & 7) * 16;
  const char* VT1 = (const char*)VTb + (size_t)((512 + tid) >> 3) * (NK * 2) + (size_t)kvbase * 2 + (tid & 7) * 16;

  auto issueLoads = [&](int step) {
    const char* ksrc = KaB + (size_t)step * (KVB * 288);
    kregA = *(const u32x4*)(ksrc + kAsrc);
    kregB = *(const u32x4*)(ksrc + kBsrc);
    if (tid < 128) kregC = *(const u32x4*)(ksrc + kCsrc);
    vreg0 = *(const u32x4*)(VT0 + (size_t)step * (KVB * 2));
    vreg1 = *(const u32x4*)(VT1 + (size_t)step * (KVB * 2));
  };
  auto writeLds = [&](int buf) {
    char* kd = ldsK + buf * KTILE;
    *(u32x4*)(kd + kAdst) = kregA;
    *(u32x4*)(kd + kBdst) = kregB;
    if (tid < 128) *(u32x4*)(kd + kCdst) = kregC;
    char* vd = ldsV + buf * VTILE;
    *(u32x4*)(vd + vAdst) = vreg0;
    *(u32x4*)(vd + vBdst) = vreg1;
  };

  issueLoads(0);
  writeLds(0);
  __syncthreads();

  for (int t = 0; t < STEPS; ++t) {
    const int cur = t & 1;
    if (t < STEPS - 1) issueLoads(t + 1);  // T14: issue early, write after compute

    const char* kb = ldsK + cur * KTILE;
    const char* vb = ldsV + cur * VTILE;

#pragma unroll
    for (int hh = 0; hh < 2; ++hh) {
      // ---- swapped QK^T: S^T tile (kv rows hh*32.., q col = ln31), dual chains ----
      f32x16 sA, sB;
#pragma unroll
      for (int r = 0; r < 16; ++r) { sA[r] = 0.0f; sB[r] = 0.0f; }
      const char* kbh = kb + (hh * 32 + ln31) * KSTRIDE + hi * 16;
      __builtin_amdgcn_s_setprio(1);
#pragma unroll
      for (int sl = 0; sl < 9; ++sl) {
        const bf16x8 kf = *(const bf16x8*)(kbh + sl * 32);
        if (sl & 1)
          sB = __builtin_amdgcn_mfma_f32_32x32x16_bf16(kf, qf[sl], sB, 0, 0, 0);
        else
          sA = __builtin_amdgcn_mfma_f32_32x32x16_bf16(kf, qf[sl], sA, 0, 0, 0);
      }
      __builtin_amdgcn_s_setprio(0);

      // ---- P = exp2(s2); s2 bounded ~[-25, 6] -> no max tracking ----
      float p[16];
#pragma unroll
      for (int r = 0; r < 16; ++r) p[r] = exp2f(sA[r] + sB[r]);
      {
        float t0 = (p[0] + p[1]) + (p[2] + p[3]);
        float t1 = (p[4] + p[5]) + (p[6] + p[7]);
        float t2 = (p[8] + p[9]) + (p[10] + p[11]);
        float t3 = (p[12] + p[13]) + (p[14] + p[15]);
        lsum += (t0 + t1) + (t2 + t3);
      }

      // ---- pack P pairs to bf16 dwords ----
      u32 pk0, pk1, pk2, pk3, pk4, pk5, pk6, pk7;
      asm("v_cvt_pk_bf16_f32 %0, %1, %2" : "=v"(pk0) : "v"(p[0]),  "v"(p[1]));
      asm("v_cvt_pk_bf16_f32 %0, %1, %2" : "=v"(pk1) : "v"(p[2]),  "v"(p[3]));
      asm("v_cvt_pk_bf16_f32 %0, %1, %2" : "=v"(pk2) : "v"(p[4]),  "v"(p[5]));
      asm("v_cvt_pk_bf16_f32 %0, %1, %2" : "=v"(pk3) : "v"(p[6]),  "v"(p[7]));
      asm("v_cvt_pk_bf16_f32 %0, %1, %2" : "=v"(pk4) : "v"(p[8]),  "v"(p[9]));
      asm("v_cvt_pk_bf16_f32 %0, %1, %2" : "=v"(pk5) : "v"(p[10]), "v"(p[11]));
      asm("v_cvt_pk_bf16_f32 %0, %1, %2" : "=v"(pk6) : "v"(p[12]), "v"(p[13]));
      asm("v_cvt_pk_bf16_f32 %0, %1, %2" : "=v"(pk7) : "v"(p[14]), "v"(p[15]));
      const bool hb = (hi != 0);

      // ---- build P A-frags via one cross-half exchange, then PV ----
#pragma unroll
      for (int ksl = 0; ksl < 2; ++ksl) {
        const u32 a0 = ksl ? pk4 : pk0, a1 = ksl ? pk5 : pk1;
        const u32 b0 = ksl ? pk6 : pk2, b1 = ksl ? pk7 : pk3;
        const u32 own0 = hb ? b0 : a0, own1 = hb ? b1 : a1;
        const u32 snd0 = hb ? a0 : b0, snd1 = hb ? a1 : b1;
        const u32 rcv0 = (u32)__shfl_xor((int)snd0, 32);
        const u32 rcv1 = (u32)__shfl_xor((int)snd1, 32);
        union { u32x4 u; bf16x8 b; } pa;
        pa.u[0] = hb ? rcv0 : own0;
        pa.u[1] = hb ? rcv1 : own1;
        pa.u[2] = hb ? own0 : rcv0;
        pa.u[3] = hb ? own1 : rcv1;
        const char* vbh = vb + ln31 * VSTRIDE + hh * 64 + ksl * 32 + hi * 16;
        __builtin_amdgcn_s_setprio(1);
#pragma unroll
        for (int dt = 0; dt < 4; ++dt) {
          const bf16x8 vf = *(const bf16x8*)(vbh + dt * (32 * VSTRIDE));
          acc[dt] = __builtin_amdgcn_mfma_f32_32x32x16_bf16(pa.b, vf, acc[dt], 0, 0, 0);
        }
        __builtin_amdgcn_s_setprio(0);
      }
    }

    if (t < STEPS - 1) {
      writeLds(cur ^ 1);
      __syncthreads();
    }
  }

  // ---- epilogue: partner half of L, write bf16 partials ----
  lsum += __shfl_xor(lsum, 32);
  u16* op = Opart + ((size_t)ks * NQ + qrow0) * DH;
#pragma unroll
  for (int dt = 0; dt < 4; ++dt)
#pragma unroll
    for (int r = 0; r < 16; ++r) {
      const int q = (r & 3) + 8 * (r >> 2) + 4 * hi;
      op[(size_t)q * DH + dt * 32 + ln31] = f2bf(acc[dt][r]);
    }
  if (hi == 0) Lpart[(size_t)ks * NQ + qrow0 + ln31] = lsum;
}

// ---------- combine: plain sums over splits ----------
__global__ void combine(const u16* __restrict__ Opart, const float* __restrict__ Lpart,
                        const float* __restrict__ arow, float* __restrict__ out,
                        float* __restrict__ lse) {
  const int idx = blockIdx.x * 256 + threadIdx.x;
  const int row = idx >> 5;
  const int d4 = (idx & 31) * 4;
  float o0 = 0.f, o1 = 0.f, o2 = 0.f, o3 = 0.f;
  float L = 0.f;
#pragma unroll
  for (int s = 0; s < SPLITS; ++s) {
    const ushort4 v = *(const ushort4*)(Opart + ((size_t)s * NQ + row) * DH + d4);
    union { u32 u; float f; } c0, c1, c2, c3;
    c0.u = ((u32)v.x) << 16; c1.u = ((u32)v.y) << 16;
    c2.u = ((u32)v.z) << 16; c3.u = ((u32)v.w) << 16;
    o0 += c0.f; o1 += c1.f; o2 += c2.f; o3 += c3.f;
    L += Lpart[(size_t)s * NQ + row];
  }
  const float inv = 1.0f / L;
  *(float4*)(out + (size_t)row * DH + d4) =
      make_float4(o0 * inv, o1 * inv, o2 * inv, o3 * inv);
  if ((idx & 31) == 0) lse[row] = logf(L) + arow[row];
}

extern "C" void kernel_launch(void* const* d_in, const int* in_sizes, int n_in,
                              void* d_out, int out_size, void* d_ws, size_t ws_size,
                              hipStream_t stream) {
  const float* Q = (const float*)d_in[0];
  const float* K = (const float*)d_in[1];
  const float* V = (const float*)d_in[2];
  const float* h = (const float*)d_in[3];
  const float* ldq = (const float*)d_in[4];
  const float* ldk = (const float*)d_in[5];

  char* ws = (char*)d_ws;
  u16* Qa    = (u16*)(ws + 0);                       // 2359296
  u16* Ka    = (u16*)(ws + 2359296);                 // 2359296
  u16* VTb   = (u16*)(ws + 4718592);                 // 2097152
  float* arow  = (float*)(ws + 6815744);             // 32768
  u16* Opart = (u16*)(ws + 6848512);                 // 8*8192*128*2 = 16777216
  float* Lpart = (float*)(ws + 23625728);            // 8*8192*4 = 262144 (end 23887872)

  float* out = (float*)d_out;
  float* lse = out + (size_t)NQ * DH;

  // allow >64KB dynamic LDS (config call, not a stream op — capture-safe)
  hipFuncSetAttribute(reinterpret_cast<const void*>(attn_main),
                      hipFuncAttributeMaxDynamicSharedMemorySize, LDS_BYTES);

  prep_qk<<<NQ / 2, 256, 0, stream>>>(Q, ldq, K, ldk, h, Qa, Ka, arow);
  prep_vt<<<dim3(NK / 64, DH / 64), 256, 0, stream>>>(V, VTb);
  attn_main<<<(NQ / 256) * SPLITS, 512, LDS_BYTES, stream>>>(Qa, Ka, VTb, Opart, Lpart);
  combine<<<NQ * 32 / 256, 256, 0, stream>>>(Opart, Lpart, arow, out, lse);
}